// Round 7
// baseline (59.889 us; speedup 1.0000x reference)
//
#include <hip/hip_runtime.h>

typedef float f32x4 __attribute__((ext_vector_type(4)));

constexpr int BLOCK = 256;
constexpr int QPT   = 16;             // queries per thread (register tile)
constexpr int QPB   = BLOCK * QPT;    // 4096 queries per block

// Stage 1: partial per-query min over one point-slice.
// Points pre-transformed in LDS to (-2px,-2py,-2pz,|p|^2); each distance
// (minus deferred |q|^2) is 3 fma; pairs share the min: v_min3_f32.
// ALL pins are `asm volatile`: non-volatile asm (r6) is sinkable/duplicable,
// and LLVM sank the q-loads+pins into the j-loop (VGPR=52, q re-loaded from
// L1 every iteration). Volatile pins force the 48 q-floats resident.
__global__ __launch_bounds__(BLOCK, 4)
void chamfer_partial_kernel(const float* __restrict__ rec,
                            const float* __restrict__ data,
                            float* __restrict__ partial,   // [S][TOTQ]
                            int N, int M, int B, int S)
{
    extern __shared__ f32x4 pts[];    // slice points, transformed

    const int bid = blockIdx.x;
    const int qb  = bid / S;           // query-block index
    const int s   = bid % S;           // point-slice index
    const int q0  = qb * QPB;
    const int TOTQ0 = B * N;
    const int TOTQ  = B * (N + M);

    const bool dir1 = q0 >= TOTQ0;
    const int  lq0  = dir1 ? q0 - TOTQ0 : q0;
    const int  Nq   = dir1 ? M : N;
    const int  Np   = dir1 ? N : M;
    const int  b    = lq0 / Nq;

    const float* __restrict__ qbase =
        (dir1 ? data : rec) + ((size_t)b * Nq + (lq0 % Nq)) * 3;
    const float* __restrict__ pbase =
        (dir1 ? rec : data) + (size_t)b * Np * 3;

    const int slice = Np / S;
    const int p0    = s * slice;

    for (int j = threadIdx.x; j < slice; j += BLOCK) {
        const float* pp = pbase + (size_t)(p0 + j) * 3;
        const float px = pp[0], py = pp[1], pz = pp[2];
        f32x4 v = { -2.f * px, -2.f * py, -2.f * pz,
                    fmaf(px, px, fmaf(py, py, pz * pz)) };
        pts[j] = v;
    }
    __syncthreads();

    float qx[QPT], qy[QPT], qz[QPT], mn[QPT];
    #pragma unroll
    for (int k = 0; k < QPT; ++k) {
        const float* qp = qbase + (size_t)(k * BLOCK + threadIdx.x) * 3;
        qx[k] = qp[0]; qy[k] = qp[1]; qz[k] = qp[2];
        // volatile: cannot be sunk/duplicated into the j-loop -> q stays
        // in VGPRs for the whole kernel (executes exactly once).
        asm volatile("" : "+v"(qx[k]), "+v"(qy[k]), "+v"(qz[k]));
        mn[k] = 3.4e38f;
    }

    #pragma unroll 2
    for (int j = 0; j < slice; j += 2) {
        f32x4 P0 = pts[j];
        f32x4 P1 = pts[j + 1];
        // volatile: one ds_read_b128 each, value pinned whole across all
        // QPT uses (no per-use ds_read_b32 re-splitting).
        asm volatile("" : "+v"(P0), "+v"(P1));
        #pragma unroll
        for (int k = 0; k < QPT; ++k) {
            float t0 = fmaf(qz[k], P0.z, P0.w);
            t0 = fmaf(qy[k], P0.y, t0);
            t0 = fmaf(qx[k], P0.x, t0);
            float t1 = fmaf(qz[k], P1.z, P1.w);
            t1 = fmaf(qy[k], P1.y, t1);
            t1 = fmaf(qx[k], P1.x, t1);
            mn[k] = fminf(fminf(t0, t1), mn[k]);   // -> v_min3_f32
        }
        // All accumulators live HERE each iteration: no k-major fission.
        asm volatile("" : "+v"(mn[0]), "+v"(mn[1]), "+v"(mn[2]), "+v"(mn[3]),
                          "+v"(mn[4]), "+v"(mn[5]), "+v"(mn[6]), "+v"(mn[7]),
                          "+v"(mn[8]), "+v"(mn[9]), "+v"(mn[10]), "+v"(mn[11]),
                          "+v"(mn[12]), "+v"(mn[13]), "+v"(mn[14]), "+v"(mn[15]));
    }

    float* out = partial + (size_t)s * TOTQ + q0;
    #pragma unroll
    for (int k = 0; k < QPT; ++k)
        out[k * BLOCK + threadIdx.x] = mn[k];
}

// Stage 2: per query, min across S slices, add |q|^2, clamp, block-sum.
__global__ __launch_bounds__(BLOCK)
void chamfer_reduce_kernel(const float* __restrict__ rec,
                           const float* __restrict__ data,
                           const float* __restrict__ partial,
                           float* __restrict__ block_sums,
                           int N, int M, int B, int S)
{
    __shared__ float wsum[BLOCK / 64];
    const int q = blockIdx.x * BLOCK + threadIdx.x;
    const int TOTQ0 = B * N;
    const int TOTQ  = B * (N + M);

    float m0 = 3.4e38f, m1 = 3.4e38f, m2 = 3.4e38f, m3 = 3.4e38f;
    int s = 0;
    for (; s + 4 <= S; s += 4) {
        m0 = fminf(m0, partial[(size_t)(s + 0) * TOTQ + q]);
        m1 = fminf(m1, partial[(size_t)(s + 1) * TOTQ + q]);
        m2 = fminf(m2, partial[(size_t)(s + 2) * TOTQ + q]);
        m3 = fminf(m3, partial[(size_t)(s + 3) * TOTQ + q]);
    }
    for (; s < S; ++s) m0 = fminf(m0, partial[(size_t)s * TOTQ + q]);
    float mn = fminf(fminf(m0, m1), fminf(m2, m3));

    const bool dir1 = q >= TOTQ0;
    const int  lq   = dir1 ? q - TOTQ0 : q;
    const float* qp = (dir1 ? data : rec) + (size_t)lq * 3;
    const float q2  = fmaf(qp[0], qp[0], fmaf(qp[1], qp[1], qp[2] * qp[2]));
    float d = fmaxf(mn + q2, 0.0f);

    for (int off = 32; off; off >>= 1) d += __shfl_down(d, off);
    if ((threadIdx.x & 63) == 0) wsum[threadIdx.x >> 6] = d;
    __syncthreads();
    if (threadIdx.x == 0) {
        float ssum = 0.f;
        for (int w = 0; w < BLOCK / 64; ++w) ssum += wsum[w];
        block_sums[blockIdx.x] = ssum;
    }
}

// Finalize: mean_b( max(sum_rec/N, sum_data/M) )
__global__ __launch_bounds__(256)
void chamfer_finalize(const float* __restrict__ bs, float* __restrict__ out,
                      int N, int M, int B)
{
    __shared__ float smem[256];
    __shared__ float seg[16];
    const int nb0 = N / BLOCK, nb1 = M / BLOCK;
    const int nblk = B * (nb0 + nb1);
    const int tid = threadIdx.x;
    smem[tid] = (tid < nblk) ? bs[tid] : 0.f;
    __syncthreads();
    if (tid < 2 * B) {
        const int dir = tid / B, b = tid % B;
        const int cnt = dir ? nb1 : nb0;
        const int off = dir ? B * nb0 + b * nb1 : b * nb0;
        float v = 0.f;
        for (int i = 0; i < cnt; ++i) v += smem[off + i];
        seg[tid] = v;
    }
    __syncthreads();
    if (tid == 0) {
        float acc = 0.f;
        for (int b = 0; b < B; ++b)
            acc += fmaxf(seg[b] / (float)N, seg[B + b] / (float)M);
        out[0] = acc / (float)B;
    }
}

extern "C" void kernel_launch(void* const* d_in, const int* in_sizes, int n_in,
                              void* d_out, int out_size, void* d_ws, size_t ws_size,
                              hipStream_t stream)
{
    const float* rec  = (const float*)d_in[0];
    const float* data = (const float*)d_in[1];
    const int B = 4;
    const int N = in_sizes[0] / (B * 3);
    const int M = in_sizes[1] / (B * 3);
    const int TOTQ = B * (N + M);

    // S=64, QPT=16 -> grid 1024 = 4 blocks/CU, 16 waves/CU.
    int S = 64;
    const int nblk2 = TOTQ / BLOCK;                    // stage-2 blocks
    while (S > 1 &&
           (size_t)S * TOTQ * sizeof(float) + (size_t)nblk2 * sizeof(float) > ws_size)
        S >>= 1;

    float* partial    = (float*)d_ws;                  // [S][TOTQ]
    float* block_sums = partial + (size_t)S * TOTQ;    // [nblk2]

    const int grid1   = (TOTQ / QPB) * S;
    const int maxNp   = (N > M) ? N : M;
    const size_t lds1 = (size_t)(maxNp / S) * sizeof(f32x4);

    chamfer_partial_kernel<<<grid1, BLOCK, lds1, stream>>>(rec, data, partial,
                                                           N, M, B, S);
    chamfer_reduce_kernel<<<nblk2, BLOCK, 0, stream>>>(rec, data, partial,
                                                       block_sums, N, M, B, S);
    chamfer_finalize<<<1, 256, 0, stream>>>(block_sums, (float*)d_out, N, M, B);
}

// Round 8
// 52.651 us; speedup vs baseline: 1.1375x; 1.1375x over previous
//
#include <hip/hip_runtime.h>

typedef float f32x4 __attribute__((ext_vector_type(4)));

constexpr int BLOCK = 256;
constexpr int QPT   = 4;              // queries per thread: state ~28 VGPRs,
                                      // BELOW any pressure threshold (r2-r7
                                      // showed the allocator mangles larger
                                      // q-tiles; this removes the fight).
constexpr int QPB   = BLOCK * QPT;    // 1024 queries per block

// Stage 1: partial per-query min over one point-slice.
// Points pre-transformed in LDS to (-2px,-2py,-2pz,|p|^2); each distance
// (minus deferred |q|^2) is 3 fma; pairs share the min via v_min3_f32
// (3.5 VALU/dist). ILP: 4 queries x 2 points = 8 independent chains, and at
// 4 waves/SIMD the issue gap (~8 cyc) exceeds fma latency (~4 cyc) anyway.
__global__ __launch_bounds__(BLOCK, 8)
void chamfer_partial_kernel(const float* __restrict__ rec,
                            const float* __restrict__ data,
                            float* __restrict__ partial,   // [S][TOTQ]
                            int N, int M, int B, int S)
{
    extern __shared__ f32x4 pts[];    // slice points, transformed

    const int bid = blockIdx.x;
    const int qb  = bid / S;           // query-block index
    const int s   = bid % S;           // point-slice index
    const int q0  = qb * QPB;
    const int TOTQ0 = B * N;
    const int TOTQ  = B * (N + M);

    const bool dir1 = q0 >= TOTQ0;
    const int  lq0  = dir1 ? q0 - TOTQ0 : q0;
    const int  Nq   = dir1 ? M : N;
    const int  Np   = dir1 ? N : M;
    const int  b    = lq0 / Nq;

    const float* __restrict__ qbase =
        (dir1 ? data : rec) + ((size_t)b * Nq + (lq0 % Nq)) * 3;
    const float* __restrict__ pbase =
        (dir1 ? rec : data) + (size_t)b * Np * 3;

    const int slice = Np / S;
    const int p0    = s * slice;

    for (int j = threadIdx.x; j < slice; j += BLOCK) {
        const float* pp = pbase + (size_t)(p0 + j) * 3;
        const float px = pp[0], py = pp[1], pz = pp[2];
        f32x4 v = { -2.f * px, -2.f * py, -2.f * pz,
                    fmaf(px, px, fmaf(py, py, pz * pz)) };
        pts[j] = v;
    }
    __syncthreads();

    float qx[QPT], qy[QPT], qz[QPT], mn[QPT];
    #pragma unroll
    for (int k = 0; k < QPT; ++k) {
        const float* qp = qbase + (size_t)(k * BLOCK + threadIdx.x) * 3;
        qx[k] = qp[0]; qy[k] = qp[1]; qz[k] = qp[2];
        mn[k] = 3.4e38f;
    }

    #pragma unroll 2
    for (int j = 0; j < slice; j += 2) {
        const f32x4 P0 = pts[j];
        const f32x4 P1 = pts[j + 1];
        #pragma unroll
        for (int k = 0; k < QPT; ++k) {
            float t0 = fmaf(qz[k], P0.z, P0.w);
            t0 = fmaf(qy[k], P0.y, t0);
            t0 = fmaf(qx[k], P0.x, t0);
            float t1 = fmaf(qz[k], P1.z, P1.w);
            t1 = fmaf(qy[k], P1.y, t1);
            t1 = fmaf(qx[k], P1.x, t1);
            mn[k] = fminf(fminf(t0, t1), mn[k]);   // -> v_min3_f32
        }
    }

    float* out = partial + (size_t)s * TOTQ + q0;
    #pragma unroll
    for (int k = 0; k < QPT; ++k)
        out[k * BLOCK + threadIdx.x] = mn[k];
}

// Stage 2: per query, min across S slices, add |q|^2, clamp, block-sum.
__global__ __launch_bounds__(BLOCK)
void chamfer_reduce_kernel(const float* __restrict__ rec,
                           const float* __restrict__ data,
                           const float* __restrict__ partial,
                           float* __restrict__ block_sums,
                           int N, int M, int B, int S)
{
    __shared__ float wsum[BLOCK / 64];
    const int q = blockIdx.x * BLOCK + threadIdx.x;
    const int TOTQ0 = B * N;
    const int TOTQ  = B * (N + M);

    float m0 = 3.4e38f, m1 = 3.4e38f, m2 = 3.4e38f, m3 = 3.4e38f;
    int s = 0;
    for (; s + 4 <= S; s += 4) {
        m0 = fminf(m0, partial[(size_t)(s + 0) * TOTQ + q]);
        m1 = fminf(m1, partial[(size_t)(s + 1) * TOTQ + q]);
        m2 = fminf(m2, partial[(size_t)(s + 2) * TOTQ + q]);
        m3 = fminf(m3, partial[(size_t)(s + 3) * TOTQ + q]);
    }
    for (; s < S; ++s) m0 = fminf(m0, partial[(size_t)s * TOTQ + q]);
    float mn = fminf(fminf(m0, m1), fminf(m2, m3));

    const bool dir1 = q >= TOTQ0;
    const int  lq   = dir1 ? q - TOTQ0 : q;
    const float* qp = (dir1 ? data : rec) + (size_t)lq * 3;
    const float q2  = fmaf(qp[0], qp[0], fmaf(qp[1], qp[1], qp[2] * qp[2]));
    float d = fmaxf(mn + q2, 0.0f);

    for (int off = 32; off; off >>= 1) d += __shfl_down(d, off);
    if ((threadIdx.x & 63) == 0) wsum[threadIdx.x >> 6] = d;
    __syncthreads();
    if (threadIdx.x == 0) {
        float ssum = 0.f;
        for (int w = 0; w < BLOCK / 64; ++w) ssum += wsum[w];
        block_sums[blockIdx.x] = ssum;
    }
}

// Finalize: mean_b( max(sum_rec/N, sum_data/M) )
__global__ __launch_bounds__(256)
void chamfer_finalize(const float* __restrict__ bs, float* __restrict__ out,
                      int N, int M, int B)
{
    __shared__ float smem[256];
    __shared__ float seg[16];
    const int nb0 = N / BLOCK, nb1 = M / BLOCK;
    const int nblk = B * (nb0 + nb1);
    const int tid = threadIdx.x;
    smem[tid] = (tid < nblk) ? bs[tid] : 0.f;
    __syncthreads();
    if (tid < 2 * B) {
        const int dir = tid / B, b = tid % B;
        const int cnt = dir ? nb1 : nb0;
        const int off = dir ? B * nb0 + b * nb1 : b * nb0;
        float v = 0.f;
        for (int i = 0; i < cnt; ++i) v += smem[off + i];
        seg[tid] = v;
    }
    __syncthreads();
    if (tid == 0) {
        float acc = 0.f;
        for (int b = 0; b < B; ++b)
            acc += fmaxf(seg[b] / (float)N, seg[B + b] / (float)M);
        out[0] = acc / (float)B;
    }
}

extern "C" void kernel_launch(void* const* d_in, const int* in_sizes, int n_in,
                              void* d_out, int out_size, void* d_ws, size_t ws_size,
                              hipStream_t stream)
{
    const float* rec  = (const float*)d_in[0];
    const float* data = (const float*)d_in[1];
    const int B = 4;
    const int N = in_sizes[0] / (B * 3);
    const int M = in_sizes[1] / (B * 3);
    const int TOTQ = B * (N + M);

    // QPT=4, S=16 -> grid (TOTQ/1024)*16 = 1024 blocks = 4/CU = 4 waves/SIMD.
    // partial = 16 * 65536 * 4B = 4.2 MB.
    int S = 16;
    const int nblk2 = TOTQ / BLOCK;                    // stage-2 blocks
    while (S > 1 &&
           (size_t)S * TOTQ * sizeof(float) + (size_t)nblk2 * sizeof(float) > ws_size)
        S >>= 1;

    float* partial    = (float*)d_ws;                  // [S][TOTQ]
    float* block_sums = partial + (size_t)S * TOTQ;    // [nblk2]

    const int grid1   = (TOTQ / QPB) * S;
    const int maxNp   = (N > M) ? N : M;
    const size_t lds1 = (size_t)(maxNp / S) * sizeof(f32x4);

    chamfer_partial_kernel<<<grid1, BLOCK, lds1, stream>>>(rec, data, partial,
                                                           N, M, B, S);
    chamfer_reduce_kernel<<<nblk2, BLOCK, 0, stream>>>(rec, data, partial,
                                                       block_sums, N, M, B, S);
    chamfer_finalize<<<1, 256, 0, stream>>>(block_sums, (float*)d_out, N, M, B);
}